// Round 1
// baseline (698.032 us; speedup 1.0000x reference)
//
#include <hip/hip_runtime.h>

// Problem constants (from reference)
#define NB 64     // batch
#define NI 2048   // input capsules
#define ND 16     // d_in
#define NJ 32     // output capsules
#define NE 32     // d_out

constexpr int BB = 8;          // batches per block
constexpr int IC = 32;         // input capsules per block (i-chunk)
constexpr int NCH = NI / IC;   // 64 chunks

__device__ inline float dot4(float4 a, float4 b) {
    return a.x * b.x + a.y * b.y + a.z * b.z + a.w * b.w;
}

// Routing round kernel.
// grid (NCH=64, NB/BB=8)  -> linear id = ch + 64*bb, so the 8 b-blocks of one
// i-chunk map to the same XCD under round-robin dispatch (W L2 reuse).
// block = 512 threads: j = t>>4 (32), eo = t&15 (16 e-pairs; e = 2*eo, 2*eo+1)
template <int ROUND>
__global__ __launch_bounds__(512, 4)
void routing_k(const float* __restrict__ x,     // [NB][NI][ND]
               const float* __restrict__ W,     // [NJ][NI][NE][ND]
               const float* __restrict__ Oacc,  // [NB][NJ][NE] (sum of prior outputs)
               float* __restrict__ s)           // [NB][NJ][NE] (atomic accum)
{
    const int ch = blockIdx.x;
    const int bb = blockIdx.y;
    const int i0 = ch * IC;
    const int b0 = bb * BB;
    const int t  = threadIdx.x;
    const int j  = t >> 4;
    const int eo = t & 15;

    __shared__ float x_lds[IC][BB][ND];     // 16 KB
    __shared__ float oacc_lds[BB][NJ][NE];  // 32 KB (unused data in ROUND 0)
    __shared__ float logit_lds[BB][NJ];     // 1 KB
    __shared__ float c_lds[BB][NJ];         // 1 KB

    // Stage x tile: 8 b * 32 i * 16 d = 4096 floats = 1024 float4, 2/thread.
    {
        const float4* xg = reinterpret_cast<const float4*>(x);
        float4* xl = reinterpret_cast<float4*>(&x_lds[0][0][0]);
#pragma unroll
        for (int k = 0; k < 2; ++k) {
            int q   = t * 2 + k;     // 0..1023
            int b_l = q >> 7;        // 0..7
            int rem = q & 127;
            int i_l = rem >> 2;      // 0..31
            int dq  = rem & 3;       // 0..3
            float4 v = xg[((size_t)(b0 + b_l) * NI + (i0 + i_l)) * 4 + dq];
            xl[(i_l * BB + b_l) * 4 + dq] = v;
        }
    }
    // Stage Oacc slice for our 8 batches: 8192 floats = 2048 float4, 4/thread.
    if (ROUND > 0) {
        const float4* og = reinterpret_cast<const float4*>(Oacc + (size_t)b0 * NJ * NE);
        float4* ol = reinterpret_cast<float4*>(&oacc_lds[0][0][0]);
#pragma unroll
        for (int k = 0; k < 4; ++k) ol[t + 512 * k] = og[t + 512 * k];
    }
    __syncthreads();

    float sacc0[BB], sacc1[BB];
#pragma unroll
    for (int b = 0; b < BB; ++b) { sacc0[b] = 0.f; sacc1[b] = 0.f; }

    float u0s[BB], u1s[BB];

    for (int i_l = 0; i_l < IC; ++i_l) {
        const int i = i0 + i_l;
        // Per-thread W fragment: rows e=2*eo and 2*eo+1, all 16 d. 32 floats.
        const float4* Wp = reinterpret_cast<const float4*>(
            W + (((size_t)j * NI + i) * NE + (size_t)eo * 2) * ND);
        float4 w0 = Wp[0], w1 = Wp[1], w2 = Wp[2], w3 = Wp[3];
        float4 w4 = Wp[4], w5 = Wp[5], w6 = Wp[6], w7 = Wp[7];

        // Phase A: u_hat fragments for all 8 batches (+ logit partials)
#pragma unroll
        for (int b = 0; b < BB; ++b) {
            const float4* xv = reinterpret_cast<const float4*>(&x_lds[i_l][b][0]);
            float4 x0 = xv[0], x1 = xv[1], x2 = xv[2], x3 = xv[3];
            float u0 = dot4(x0, w0) + dot4(x1, w1) + dot4(x2, w2) + dot4(x3, w3);
            float u1 = dot4(x0, w4) + dot4(x1, w5) + dot4(x2, w6) + dot4(x3, w7);
            u0s[b] = u0;
            u1s[b] = u1;
            if (ROUND > 0) {
                float lp = u0 * oacc_lds[b][j][2 * eo] + u1 * oacc_lds[b][j][2 * eo + 1];
                // reduce over the 16 e-pair lanes (consecutive lanes per j)
                lp += __shfl_xor(lp, 1, 16);
                lp += __shfl_xor(lp, 2, 16);
                lp += __shfl_xor(lp, 4, 16);
                lp += __shfl_xor(lp, 8, 16);
                if (eo == 0) logit_lds[b][j] = lp;
            }
        }

        // Phase B: softmax over j for each (b, i) — 256 workers
        if (ROUND > 0) {
            __syncthreads();
            if (t < BB * NJ) {
                const int lb = t >> 5, lj = t & 31;
                float v = logit_lds[lb][lj];
                float m = v;
#pragma unroll
                for (int mk = 16; mk >= 1; mk >>= 1)
                    m = fmaxf(m, __shfl_xor(m, mk, 32));
                float ev = __expf(v - m);
                float sm = ev;
#pragma unroll
                for (int mk = 16; mk >= 1; mk >>= 1)
                    sm += __shfl_xor(sm, mk, 32);
                c_lds[lb][lj] = ev / sm;
            }
            __syncthreads();
        }

        // Phase C: weighted accumulation into per-thread partial s
#pragma unroll
        for (int b = 0; b < BB; ++b) {
            const float c = (ROUND == 0) ? (1.0f / NJ) : c_lds[b][j];
            sacc0[b] += c * u0s[b];
            sacc1[b] += c * u1s[b];
        }
    }

    // Tail: one atomic per owned output element per block.
#pragma unroll
    for (int b = 0; b < BB; ++b) {
        float* sp = s + ((size_t)(b0 + b) * NJ + j) * NE + 2 * eo;
        atomicAdd(sp, sacc0[b]);
        atomicAdd(sp + 1, sacc1[b]);
    }
}

// Squash + state update. grid 64 (b), block 256: j = t>>3, eq = t&7 (4 e's).
// Reads s, re-zeros it for the next round's atomics, then either accumulates
// into Oacc (non-final) or writes d_out (final).
__global__ void squash_k(float* __restrict__ s, float* __restrict__ Oacc,
                         float* __restrict__ out, int final_round)
{
    const int b = blockIdx.x;
    const int t = threadIdx.x;
    const int j = t >> 3;
    const int eq = t & 7;
    const size_t off = ((size_t)b * NJ + j) * NE + 4 * eq;

    float4* sp = reinterpret_cast<float4*>(s + off);
    float4 v = *sp;
    *sp = make_float4(0.f, 0.f, 0.f, 0.f);

    float p = v.x * v.x + v.y * v.y + v.z * v.z + v.w * v.w;
    p += __shfl_xor(p, 1, 8);
    p += __shfl_xor(p, 2, 8);
    p += __shfl_xor(p, 4, 8);

    const float scale = p / ((1.0f + p) * sqrtf(p + 1e-7f));
    float4 o = make_float4(scale * v.x, scale * v.y, scale * v.z, scale * v.w);

    if (final_round) {
        *reinterpret_cast<float4*>(out + off) = o;
    } else {
        float4* op = reinterpret_cast<float4*>(Oacc + off);
        float4 ov = *op;
        *op = make_float4(ov.x + o.x, ov.y + o.y, ov.z + o.z, ov.w + o.w);
    }
}

extern "C" void kernel_launch(void* const* d_in, const int* in_sizes, int n_in,
                              void* d_out, int out_size, void* d_ws, size_t ws_size,
                              hipStream_t stream)
{
    (void)in_sizes; (void)n_in; (void)out_size; (void)ws_size;
    const float* x = (const float*)d_in[0];   // [64][2048][16]
    const float* W = (const float*)d_in[1];   // [32][2048][32][16]
    float* out = (float*)d_out;               // [64][32][32]

    float* s    = (float*)d_ws;               // 65536 floats
    float* Oacc = s + NB * NJ * NE;           // 65536 floats

    // zero s and Oacc (ws is poisoned to 0xAA before every launch)
    hipMemsetAsync(d_ws, 0, (size_t)2 * NB * NJ * NE * sizeof(float), stream);

    dim3 grid(NCH, NB / BB);

    routing_k<0><<<grid, 512, 0, stream>>>(x, W, Oacc, s);
    squash_k<<<NB, 256, 0, stream>>>(s, Oacc, out, 0);

    routing_k<1><<<grid, 512, 0, stream>>>(x, W, Oacc, s);
    squash_k<<<NB, 256, 0, stream>>>(s, Oacc, out, 0);

    routing_k<1><<<grid, 512, 0, stream>>>(x, W, Oacc, s);
    squash_k<<<NB, 256, 0, stream>>>(s, Oacc, out, 1);
}

// Round 2
// 590.779 us; speedup vs baseline: 1.1815x; 1.1815x over previous
//
#include <hip/hip_runtime.h>

#define NB 64     // batch
#define NI 2048   // input capsules
#define ND 16     // d_in
#define NJ 32     // output capsules
#define NE 32     // d_out

typedef __attribute__((ext_vector_type(8))) short bfrag;   // 8 bf16 (4 VGPRs)
typedef __attribute__((ext_vector_type(4))) float f32x4;

// float -> bf16 bits, round-to-nearest-even
__device__ inline short f2bf(float f) {
    unsigned u = __float_as_uint(f);
    unsigned r = u + 0x7fffu + ((u >> 16) & 1u);
    return (short)(r >> 16);
}

// add value rotated by N within each 16-lane DPP row (row_ror:N)
template <int N>
__device__ inline float rot16_add(float v) {
    int r = __builtin_amdgcn_mov_dpp(__float_as_int(v), 0x120 + N, 0xf, 0xf, false);
    return v + __int_as_float(r);
}

// ---------------------------------------------------------------------------
// logits_k: lgt[b][i][j] = sum_e Oacc[b,j,e] * u_hat[b,j,i,e]
// u_hat via mfma_16x16x32_bf16 with K zero-padded (d=16): A = x[b][d], B = W[e][d].
// grid (j=32, i-chunk=64 of 32 i's), block 256 = 4 waves; wave = 16-b M-tile.
// ---------------------------------------------------------------------------
__global__ __launch_bounds__(256) void logits_k(
    const float* __restrict__ x,      // [NB][NI][ND]
    const float* __restrict__ W,      // [NJ][NI][NE][ND]
    const float* __restrict__ Oacc,   // [NB][NJ][NE]
    float* __restrict__ lgt)          // [NB][NI][NJ]
{
    const int j    = blockIdx.x;
    const int i0   = blockIdx.y * 32;
    const int t    = threadIdx.x;
    const int wv   = t >> 6;
    const int ln   = t & 63;
    const int m    = ln & 15;
    const int quad = ln >> 4;

    // Hoist Oacc fragments: rows b = wv*16 + quad*4 + r, cols e = m / 16+m
    float O0[4], O1[4];
#pragma unroll
    for (int r = 0; r < 4; ++r) {
        int b = wv * 16 + quad * 4 + r;
        O0[r] = Oacc[((size_t)b * NJ + j) * NE + m];
        O1[r] = Oacc[((size_t)b * NJ + j) * NE + 16 + m];
    }

    const int  bA  = wv * 16 + m;   // A-operand row (b) this lane supplies
    const bool act = quad < 2;      // quads 0,1 carry k=0..15 (d); 2,3 are zero pad
    const int  d0  = quad * 8;

    for (int il = 0; il < 32; ++il) {
        const int i = i0 + il;
        bfrag av = (bfrag)0, bv0 = (bfrag)0, bv1 = (bfrag)0;
        if (act) {
            const float* xp  = x + ((size_t)bA * NI + i) * ND + d0;
            const float* wp0 = W + (((size_t)j * NI + i) * NE + m) * ND + d0;
            const float* wp1 = wp0 + 16 * ND;
#pragma unroll
            for (int q = 0; q < 8; ++q) {
                av[q]  = f2bf(xp[q]);
                bv0[q] = f2bf(wp0[q]);
                bv1[q] = f2bf(wp1[q]);
            }
        }
        f32x4 z = {0.f, 0.f, 0.f, 0.f};
        f32x4 U0 = __builtin_amdgcn_mfma_f32_16x16x32_bf16(av, bv0, z, 0, 0, 0);
        f32x4 U1 = __builtin_amdgcn_mfma_f32_16x16x32_bf16(av, bv1, z, 0, 0, 0);

        float lp[4];
#pragma unroll
        for (int r = 0; r < 4; ++r) {
            float v = U0[r] * O0[r] + U1[r] * O1[r];
            v = rot16_add<1>(v);
            v = rot16_add<2>(v);
            v = rot16_add<4>(v);
            v = rot16_add<8>(v);
            lp[r] = v;   // full sum over 32 e's, replicated across the 16-lane row
        }
        if (m == 0) {
#pragma unroll
            for (int r = 0; r < 4; ++r) {
                int b = wv * 16 + quad * 4 + r;
                lgt[((size_t)b * NI + i) * NJ + j] = lp[r];
            }
        }
    }
}

// ---------------------------------------------------------------------------
// softmax_k: in-place softmax over j (last dim, 32 contiguous floats per row)
// one thread per (b,i) row. grid 512 x 256 = 131072 rows.
// ---------------------------------------------------------------------------
__global__ __launch_bounds__(256) void softmax_k(float* __restrict__ lgt)
{
    size_t rid = (size_t)blockIdx.x * 256 + threadIdx.x;
    float4* p = reinterpret_cast<float4*>(lgt + rid * NJ);
    float4 v[8];
#pragma unroll
    for (int q = 0; q < 8; ++q) v[q] = p[q];
    float mx = -1e30f;
#pragma unroll
    for (int q = 0; q < 8; ++q) {
        mx = fmaxf(mx, fmaxf(fmaxf(v[q].x, v[q].y), fmaxf(v[q].z, v[q].w)));
    }
    float sum = 0.f;
#pragma unroll
    for (int q = 0; q < 8; ++q) {
        v[q].x = __expf(v[q].x - mx); v[q].y = __expf(v[q].y - mx);
        v[q].z = __expf(v[q].z - mx); v[q].w = __expf(v[q].w - mx);
        sum += v[q].x + v[q].y + v[q].z + v[q].w;
    }
    float inv = 1.0f / sum;
#pragma unroll
    for (int q = 0; q < 8; ++q) {
        v[q].x *= inv; v[q].y *= inv; v[q].z *= inv; v[q].w *= inv;
        p[q] = v[q];
    }
}

// ---------------------------------------------------------------------------
// wsum_k: s[b,j,e] += sum_{i in chunk} c[b,j,i] * u_hat[b,j,i,e]
// as per-j GEMM: A[b][(i,d)] = c*x (bf16, built inline), B[e][(i,d)] = W.
// K=32 MFMA chunk covers 2 i's (k = i_sel*16 + d). Split-K over 64 chunks,
// atomicAdd tail. grid (j=32, kc=64), block 128 = 2 waves; wave = 2 M-tiles.
// ---------------------------------------------------------------------------
template <bool R0>
__global__ __launch_bounds__(128) void wsum_k(
    const float* __restrict__ x,      // [NB][NI][ND]
    const float* __restrict__ W,      // [NJ][NI][NE][ND]
    const float* __restrict__ c,      // [NB][NI][NJ] (post-softmax), unused if R0
    float* __restrict__ s)            // [NB][NJ][NE]
{
    const int j    = blockIdx.x;
    const int i0   = blockIdx.y * 32;
    const int t    = threadIdx.x;
    const int wv   = t >> 6;
    const int ln   = t & 63;
    const int m    = ln & 15;
    const int quad = ln >> 4;
    const int isel = quad >> 1;        // which of the 2 i's in the K-chunk
    const int d0   = (quad & 1) * 8;   // which 8 d's

    f32x4 acc[2][2];
#pragma unroll
    for (int a = 0; a < 2; ++a)
#pragma unroll
        for (int n = 0; n < 2; ++n) acc[a][n] = (f32x4){0.f, 0.f, 0.f, 0.f};

    for (int it = 0; it < 16; ++it) {
        const int ia = i0 + it * 2 + isel;
        // B fragments (shared across M-tiles)
        bfrag bv0, bv1;
        {
            const float* wp0 = W + (((size_t)j * NI + ia) * NE + m) * ND + d0;
            const float* wp1 = wp0 + 16 * ND;
#pragma unroll
            for (int q = 0; q < 8; ++q) { bv0[q] = f2bf(wp0[q]); bv1[q] = f2bf(wp1[q]); }
        }
#pragma unroll
        for (int mt = 0; mt < 2; ++mt) {
            const int b = (wv * 2 + mt) * 16 + m;
            const float* xp = x + ((size_t)b * NI + ia) * ND + d0;
            const float cc = R0 ? (1.0f / NJ) : c[((size_t)b * NI + ia) * NJ + j];
            bfrag av;
#pragma unroll
            for (int q = 0; q < 8; ++q) av[q] = f2bf(xp[q] * cc);
            acc[mt][0] = __builtin_amdgcn_mfma_f32_16x16x32_bf16(av, bv0, acc[mt][0], 0, 0, 0);
            acc[mt][1] = __builtin_amdgcn_mfma_f32_16x16x32_bf16(av, bv1, acc[mt][1], 0, 0, 0);
        }
    }

#pragma unroll
    for (int mt = 0; mt < 2; ++mt)
#pragma unroll
        for (int nt = 0; nt < 2; ++nt)
#pragma unroll
            for (int r = 0; r < 4; ++r) {
                const int b = (wv * 2 + mt) * 16 + quad * 4 + r;
                const int e = nt * 16 + m;
                atomicAdd(&s[((size_t)b * NJ + j) * NE + e], acc[mt][nt][r]);
            }
}

// ---------------------------------------------------------------------------
// squash_k: squash(s) -> out or Oacc accumulation; re-zeros s for next round.
// ---------------------------------------------------------------------------
__global__ void squash_k(float* __restrict__ s, float* __restrict__ Oacc,
                         float* __restrict__ out, int final_round)
{
    const int b = blockIdx.x;
    const int t = threadIdx.x;
    const int j = t >> 3;
    const int eq = t & 7;
    const size_t off = ((size_t)b * NJ + j) * NE + 4 * eq;

    float4* sp = reinterpret_cast<float4*>(s + off);
    float4 v = *sp;
    *sp = make_float4(0.f, 0.f, 0.f, 0.f);

    float p = v.x * v.x + v.y * v.y + v.z * v.z + v.w * v.w;
    p += __shfl_xor(p, 1, 8);
    p += __shfl_xor(p, 2, 8);
    p += __shfl_xor(p, 4, 8);

    const float scale = p / ((1.0f + p) * sqrtf(p + 1e-7f));
    float4 o = make_float4(scale * v.x, scale * v.y, scale * v.z, scale * v.w);

    if (final_round) {
        *reinterpret_cast<float4*>(out + off) = o;
    } else {
        float4* op = reinterpret_cast<float4*>(Oacc + off);
        float4 ov = *op;
        *op = make_float4(ov.x + o.x, ov.y + o.y, ov.z + o.z, ov.w + o.w);
    }
}

extern "C" void kernel_launch(void* const* d_in, const int* in_sizes, int n_in,
                              void* d_out, int out_size, void* d_ws, size_t ws_size,
                              hipStream_t stream)
{
    (void)in_sizes; (void)n_in; (void)out_size; (void)ws_size;
    const float* x = (const float*)d_in[0];   // [64][2048][16]
    const float* W = (const float*)d_in[1];   // [32][2048][32][16]
    float* out = (float*)d_out;               // [64][32][32]

    float* s    = (float*)d_ws;               // 65536 floats
    float* Oacc = s + NB * NJ * NE;           // 65536 floats
    float* lgt  = Oacc + NB * NJ * NE;        // 64*2048*32 floats = 16 MB

    // zero s and Oacc (ws is poisoned to 0xAA before every launch)
    hipMemsetAsync(d_ws, 0, (size_t)2 * NB * NJ * NE * sizeof(float), stream);

    dim3 gG(NJ, NI / 32);   // 32 x 64 blocks

    // round 0: uniform c = 1/32
    wsum_k<true><<<gG, 128, 0, stream>>>(x, W, lgt, s);
    squash_k<<<NB, 256, 0, stream>>>(s, Oacc, out, 0);

    // round 1
    logits_k<<<gG, 256, 0, stream>>>(x, W, Oacc, lgt);
    softmax_k<<<NB * NI / 256, 256, 0, stream>>>(lgt);
    wsum_k<false><<<gG, 128, 0, stream>>>(x, W, lgt, s);
    squash_k<<<NB, 256, 0, stream>>>(s, Oacc, out, 0);

    // round 2
    logits_k<<<gG, 256, 0, stream>>>(x, W, Oacc, lgt);
    softmax_k<<<NB * NI / 256, 256, 0, stream>>>(lgt);
    wsum_k<false><<<gG, 128, 0, stream>>>(x, W, lgt, s);
    squash_k<<<NB, 256, 0, stream>>>(s, Oacc, out, 1);
}

// Round 3
// 509.671 us; speedup vs baseline: 1.3696x; 1.1591x over previous
//
#include <hip/hip_runtime.h>

#define NB 64     // batch
#define NI 2048   // input capsules
#define ND 16     // d_in
#define NJ 32     // output capsules
#define NE 32     // d_out
#define NIP (NI/2)  // i-pairs

typedef __attribute__((ext_vector_type(8))) short bfrag;   // 8 bf16 (4 VGPRs)
typedef __attribute__((ext_vector_type(4))) float f32x4;

// float -> bf16 bits, round-to-nearest-even
__device__ inline short f2bf(float f) {
    unsigned u = __float_as_uint(f);
    unsigned r = u + 0x7fffu + ((u >> 16) & 1u);
    return (short)(r >> 16);
}

// add value rotated by N within each 16-lane DPP row (row_ror:N)
template <int N>
__device__ inline float rot16_add(float v) {
    int r = __builtin_amdgcn_mov_dpp(__float_as_int(v), 0x120 + N, 0xf, 0xf, false);
    return v + __int_as_float(r);
}

// ---------------------------------------------------------------------------
// convw_k: W fp32 [NJ][NI][NE][ND] -> Wb bf16 [NJ][NIP][NE][32],
// Wb[j][ip][e][k] = W[j][ip*2 + (k>>4)][e][k&15]  (MFMA B-fragment layout,
// K=32 chunk = 2 i's x 16 d). One thread per (j,ip,e,isel): 64B read, 32B write.
// ---------------------------------------------------------------------------
__global__ __launch_bounds__(256) void convw_k(const float* __restrict__ W,
                                               short* __restrict__ Wb)
{
    const int t = blockIdx.x * 256 + threadIdx.x;   // 2^21 threads
    const int isel = t & 1;
    const int e    = (t >> 1) & 31;
    const int ip   = (t >> 6) & 1023;
    const int j    = t >> 16;

    const float4* src = reinterpret_cast<const float4*>(
        W + (((size_t)j * NI + ip * 2 + isel) * NE + e) * ND);
    float4 a = src[0], b = src[1], c = src[2], d = src[3];

    bfrag lo, hi;
    lo[0] = f2bf(a.x); lo[1] = f2bf(a.y); lo[2] = f2bf(a.z); lo[3] = f2bf(a.w);
    lo[4] = f2bf(b.x); lo[5] = f2bf(b.y); lo[6] = f2bf(b.z); lo[7] = f2bf(b.w);
    hi[0] = f2bf(c.x); hi[1] = f2bf(c.y); hi[2] = f2bf(c.z); hi[3] = f2bf(c.w);
    hi[4] = f2bf(d.x); hi[5] = f2bf(d.y); hi[6] = f2bf(d.z); hi[7] = f2bf(d.w);

    short* dst = Wb + ((((size_t)j * NIP + ip) * NE + e) * 32) + isel * 16;
    *reinterpret_cast<bfrag*>(dst)     = lo;
    *reinterpret_cast<bfrag*>(dst + 8) = hi;
}

// convx_k: x fp32 -> xb bf16, same [NB][NI][ND] layout. 8 elems/thread.
__global__ __launch_bounds__(256) void convx_k(const float* __restrict__ x,
                                               short* __restrict__ xb)
{
    const size_t t = (size_t)blockIdx.x * 256 + threadIdx.x;  // 262144 threads
    const float4* src = reinterpret_cast<const float4*>(x + t * 8);
    float4 a = src[0], b = src[1];
    bfrag v;
    v[0] = f2bf(a.x); v[1] = f2bf(a.y); v[2] = f2bf(a.z); v[3] = f2bf(a.w);
    v[4] = f2bf(b.x); v[5] = f2bf(b.y); v[6] = f2bf(b.z); v[7] = f2bf(b.w);
    *reinterpret_cast<bfrag*>(xb + t * 8) = v;
}

// ---------------------------------------------------------------------------
// logits_k: lgt[b][j][i] = sum_e Oacc[b,j,e] * u_hat[b,j,i,e]
// u_hat via mfma_16x16x32_bf16, K zero-padded (d=16). All operands bf16
// pre-converted; B-frags straight dwordx4 loads from Wb.
// grid (j=32, i-chunk=64 of 32), block 256 = 4 waves; wave = 16-b M-tile.
// ---------------------------------------------------------------------------
__global__ __launch_bounds__(256) void logits_k(
    const short* __restrict__ xb,     // [NB][NI][ND] bf16
    const short* __restrict__ Wb,     // [NJ][NIP][NE][32] bf16
    const float* __restrict__ Oacc,   // [NB][NJ][NE]
    float* __restrict__ lgt)          // [NB][NJ][NI]
{
    const int j    = blockIdx.x;
    const int i0   = blockIdx.y * 32;
    const int t    = threadIdx.x;
    const int wv   = t >> 6;
    const int ln   = t & 63;
    const int m    = ln & 15;
    const int quad = ln >> 4;

    // Hoist Oacc fragments: rows b = wv*16 + quad*4 + r, cols e = m / 16+m
    float O0[4], O1[4];
#pragma unroll
    for (int r = 0; r < 4; ++r) {
        int b = wv * 16 + quad * 4 + r;
        O0[r] = Oacc[((size_t)b * NJ + j) * NE + m];
        O1[r] = Oacc[((size_t)b * NJ + j) * NE + 16 + m];
    }

    const int  bA  = wv * 16 + m;   // A-operand row (b) this lane supplies
    const bool act = quad < 2;      // quads 0,1 carry k=0..15 (d); 2,3 zero pad
    const int  d0  = quad * 8;

    for (int il = 0; il < 32; ++il) {
        const int i = i0 + il;
        const int ip = i >> 1, isel = i & 1;
        bfrag av = (bfrag)0, bv0 = (bfrag)0, bv1 = (bfrag)0;
        if (act) {
            av = *reinterpret_cast<const bfrag*>(
                xb + ((size_t)bA * NI + i) * ND + d0);
            const short* wp = Wb + (((size_t)j * NIP + ip) * NE + m) * 32
                                 + isel * 16 + d0;
            bv0 = *reinterpret_cast<const bfrag*>(wp);
            bv1 = *reinterpret_cast<const bfrag*>(wp + 16 * 32);
        }
        f32x4 z = {0.f, 0.f, 0.f, 0.f};
        f32x4 U0 = __builtin_amdgcn_mfma_f32_16x16x32_bf16(av, bv0, z, 0, 0, 0);
        f32x4 U1 = __builtin_amdgcn_mfma_f32_16x16x32_bf16(av, bv1, z, 0, 0, 0);

        float lp[4];
#pragma unroll
        for (int r = 0; r < 4; ++r) {
            float v = U0[r] * O0[r] + U1[r] * O1[r];
            v = rot16_add<1>(v);
            v = rot16_add<2>(v);
            v = rot16_add<4>(v);
            v = rot16_add<8>(v);
            lp[r] = v;   // full sum over 32 e's, replicated across the 16-lane row
        }
        if (m == 0) {
#pragma unroll
            for (int r = 0; r < 4; ++r) {
                int b = wv * 16 + quad * 4 + r;
                lgt[((size_t)b * NJ + j) * NI + i] = lp[r];  // single-writer lines
            }
        }
    }
}

// ---------------------------------------------------------------------------
// softmax_k: softmax over j on [b][j][i] layout, in place. One thread per
// (b,i); j-strided accesses coalesce across the 256 consecutive-i threads.
// grid (NB, NI/256).
// ---------------------------------------------------------------------------
__global__ __launch_bounds__(256) void softmax_k(float* __restrict__ lgt)
{
    const int b = blockIdx.x;
    const int i = blockIdx.y * 256 + threadIdx.x;
    float* base = lgt + (size_t)b * NJ * NI + i;

    float v[NJ];
    float mx = -1e30f;
#pragma unroll
    for (int jj = 0; jj < NJ; ++jj) {
        v[jj] = base[(size_t)jj * NI];
        mx = fmaxf(mx, v[jj]);
    }
    float sum = 0.f;
#pragma unroll
    for (int jj = 0; jj < NJ; ++jj) {
        v[jj] = __expf(v[jj] - mx);
        sum += v[jj];
    }
    const float inv = 1.0f / sum;
#pragma unroll
    for (int jj = 0; jj < NJ; ++jj) base[(size_t)jj * NI] = v[jj] * inv;
}

// ---------------------------------------------------------------------------
// wsum_k: s[b,j,e] += sum_i c[b,j,i] * u_hat[b,j,i,e]
// A[b][k] = c*x (bf16 built inline from fp32 x), B[e][k] = Wb (preconverted).
// K=32 chunk = 2 i's. Split-K over 64 chunks, atomicAdd tail.
// grid (j=32, kc=64), block 128 = 2 waves; wave = 2 M-tiles.
// ---------------------------------------------------------------------------
template <bool R0>
__global__ __launch_bounds__(128) void wsum_k(
    const float* __restrict__ x,      // [NB][NI][ND] fp32
    const short* __restrict__ Wb,     // [NJ][NIP][NE][32] bf16
    const float* __restrict__ c,      // [NB][NJ][NI], unused if R0
    float* __restrict__ s)            // [NB][NJ][NE]
{
    const int j    = blockIdx.x;
    const int ip0  = blockIdx.y * 16;  // 16 i-pairs = 32 i's
    const int t    = threadIdx.x;
    const int wv   = t >> 6;
    const int ln   = t & 63;
    const int m    = ln & 15;
    const int quad = ln >> 4;
    const int isel = quad >> 1;        // which of the 2 i's in the K-chunk
    const int d0   = (quad & 1) * 8;   // which 8 d's

    f32x4 acc[2][2];
#pragma unroll
    for (int a = 0; a < 2; ++a)
#pragma unroll
        for (int n = 0; n < 2; ++n) acc[a][n] = (f32x4){0.f, 0.f, 0.f, 0.f};

    for (int it = 0; it < 16; ++it) {
        const int ip = ip0 + it;
        const int ia = ip * 2 + isel;
        const short* wp = Wb + (((size_t)j * NIP + ip) * NE + m) * 32 + quad * 8;
        bfrag bv0 = *reinterpret_cast<const bfrag*>(wp);
        bfrag bv1 = *reinterpret_cast<const bfrag*>(wp + 16 * 32);
#pragma unroll
        for (int mt = 0; mt < 2; ++mt) {
            const int b = (wv * 2 + mt) * 16 + m;
            const float cc = R0 ? (1.0f / NJ) : c[((size_t)b * NJ + j) * NI + ia];
            const float4* xp = reinterpret_cast<const float4*>(
                x + ((size_t)b * NI + ia) * ND + d0);
            float4 x0 = xp[0], x1 = xp[1];
            bfrag av;
            av[0] = f2bf(x0.x * cc); av[1] = f2bf(x0.y * cc);
            av[2] = f2bf(x0.z * cc); av[3] = f2bf(x0.w * cc);
            av[4] = f2bf(x1.x * cc); av[5] = f2bf(x1.y * cc);
            av[6] = f2bf(x1.z * cc); av[7] = f2bf(x1.w * cc);
            acc[mt][0] = __builtin_amdgcn_mfma_f32_16x16x32_bf16(av, bv0, acc[mt][0], 0, 0, 0);
            acc[mt][1] = __builtin_amdgcn_mfma_f32_16x16x32_bf16(av, bv1, acc[mt][1], 0, 0, 0);
        }
    }

#pragma unroll
    for (int mt = 0; mt < 2; ++mt)
#pragma unroll
        for (int nt = 0; nt < 2; ++nt)
#pragma unroll
            for (int r = 0; r < 4; ++r) {
                const int b = (wv * 2 + mt) * 16 + quad * 4 + r;
                const int e = nt * 16 + m;
                atomicAdd(&s[((size_t)b * NJ + j) * NE + e], acc[mt][nt][r]);
            }
}

// ---------------------------------------------------------------------------
// squash_k: squash(s) -> out or Oacc accumulation; re-zeros s for next round.
// ---------------------------------------------------------------------------
__global__ void squash_k(float* __restrict__ s, float* __restrict__ Oacc,
                         float* __restrict__ out, int final_round)
{
    const int b = blockIdx.x;
    const int t = threadIdx.x;
    const int j = t >> 3;
    const int eq = t & 7;
    const size_t off = ((size_t)b * NJ + j) * NE + 4 * eq;

    float4* sp = reinterpret_cast<float4*>(s + off);
    float4 v = *sp;
    *sp = make_float4(0.f, 0.f, 0.f, 0.f);

    float p = v.x * v.x + v.y * v.y + v.z * v.z + v.w * v.w;
    p += __shfl_xor(p, 1, 8);
    p += __shfl_xor(p, 2, 8);
    p += __shfl_xor(p, 4, 8);

    const float scale = p / ((1.0f + p) * sqrtf(p + 1e-7f));
    float4 o = make_float4(scale * v.x, scale * v.y, scale * v.z, scale * v.w);

    if (final_round) {
        *reinterpret_cast<float4*>(out + off) = o;
    } else {
        float4* op = reinterpret_cast<float4*>(Oacc + off);
        float4 ov = *op;
        *op = make_float4(ov.x + o.x, ov.y + o.y, ov.z + o.z, ov.w + o.w);
    }
}

extern "C" void kernel_launch(void* const* d_in, const int* in_sizes, int n_in,
                              void* d_out, int out_size, void* d_ws, size_t ws_size,
                              hipStream_t stream)
{
    (void)in_sizes; (void)n_in; (void)out_size; (void)ws_size;
    const float* x = (const float*)d_in[0];   // [64][2048][16]
    const float* W = (const float*)d_in[1];   // [32][2048][32][16]
    float* out = (float*)d_out;               // [64][32][32]

    // ws layout (≈84.5 MB):
    float* s    = (float*)d_ws;                       // 64K floats   (256 KB)
    float* Oacc = s + NB * NJ * NE;                   // 64K floats   (256 KB)
    float* lgt  = Oacc + NB * NJ * NE;                // 4M floats    (16 MB)
    short* xb   = (short*)(lgt + (size_t)NB * NJ * NI);        // 2M bf16 (4 MB)
    short* Wb   = xb + (size_t)NB * NI * ND;                   // 32M bf16 (64 MB)

    // zero s and Oacc (ws is poisoned to 0xAA before every launch)
    hipMemsetAsync(d_ws, 0, (size_t)2 * NB * NJ * NE * sizeof(float), stream);

    // pre-convert W and x to bf16 (fragment layouts)
    convw_k<<<(NJ * NIP * NE * 2) / 256, 256, 0, stream>>>(W, Wb);
    convx_k<<<(NB * NI * ND / 8) / 256, 256, 0, stream>>>(x, xb);

    dim3 gG(NJ, NI / 32);   // 32 x 64 blocks

    // round 0: uniform c = 1/32
    wsum_k<true><<<gG, 128, 0, stream>>>(x, Wb, lgt, s);
    squash_k<<<NB, 256, 0, stream>>>(s, Oacc, out, 0);

    // round 1
    logits_k<<<gG, 256, 0, stream>>>(xb, Wb, Oacc, lgt);
    softmax_k<<<dim3(NB, NI / 256), 256, 0, stream>>>(lgt);
    wsum_k<false><<<gG, 128, 0, stream>>>(x, Wb, lgt, s);
    squash_k<<<NB, 256, 0, stream>>>(s, Oacc, out, 0);

    // round 2
    logits_k<<<gG, 256, 0, stream>>>(xb, Wb, Oacc, lgt);
    softmax_k<<<dim3(NB, NI / 256), 256, 0, stream>>>(lgt);
    wsum_k<false><<<gG, 128, 0, stream>>>(x, Wb, lgt, s);
    squash_k<<<NB, 256, 0, stream>>>(s, Oacc, out, 1);
}

// Round 4
// 446.359 us; speedup vs baseline: 1.5638x; 1.1418x over previous
//
#include <hip/hip_runtime.h>
#include <hip/hip_bf16.h>

#define NB 64     // batch
#define NI 2048   // input capsules
#define ND 16     // d_in
#define NJ 32     // output capsules
#define NE 32     // d_out
#define NIP (NI/2)  // i-pairs

typedef __attribute__((ext_vector_type(8))) short bfrag;   // 8 bf16 (4 VGPRs)
typedef __attribute__((ext_vector_type(4))) float f32x4;

// float -> bf16 bits, round-to-nearest-even (scalar path, conv kernels)
__device__ inline short f2bf(float f) {
    unsigned u = __float_as_uint(f);
    unsigned r = u + 0x7fffu + ((u >> 16) & 1u);
    return (short)(r >> 16);
}

// two floats -> packed bf16x2 (v_cvt_pk_bf16_f32 on gfx950), RNE
__device__ inline unsigned pk2bf(float a, float b) {
    __hip_bfloat162 h = __float22bfloat162_rn(make_float2(a, b));
    return *reinterpret_cast<unsigned*>(&h);
}

// add value rotated by N within each 16-lane DPP row (row_ror:N)
template <int N>
__device__ inline float rot16_add(float v) {
    int r = __builtin_amdgcn_mov_dpp(__float_as_int(v), 0x120 + N, 0xf, 0xf, false);
    return v + __int_as_float(r);
}

// ---------------------------------------------------------------------------
// convw_k: W fp32 [NJ][NI][NE][ND] -> Wb bf16 [NJ][NIP][NE][32],
// Wb[j][ip][e][k] = W[j][ip*2 + (k>>4)][e][k&15]  (MFMA B-fragment layout).
// ---------------------------------------------------------------------------
__global__ __launch_bounds__(256) void convw_k(const float* __restrict__ W,
                                               short* __restrict__ Wb)
{
    const int t = blockIdx.x * 256 + threadIdx.x;   // 2^21 threads
    const int isel = t & 1;
    const int e    = (t >> 1) & 31;
    const int ip   = (t >> 6) & 1023;
    const int j    = t >> 16;

    const float4* src = reinterpret_cast<const float4*>(
        W + (((size_t)j * NI + ip * 2 + isel) * NE + e) * ND);
    float4 a = src[0], b = src[1], c = src[2], d = src[3];

    bfrag lo, hi;
    lo[0] = f2bf(a.x); lo[1] = f2bf(a.y); lo[2] = f2bf(a.z); lo[3] = f2bf(a.w);
    lo[4] = f2bf(b.x); lo[5] = f2bf(b.y); lo[6] = f2bf(b.z); lo[7] = f2bf(b.w);
    hi[0] = f2bf(c.x); hi[1] = f2bf(c.y); hi[2] = f2bf(c.z); hi[3] = f2bf(c.w);
    hi[4] = f2bf(d.x); hi[5] = f2bf(d.y); hi[6] = f2bf(d.z); hi[7] = f2bf(d.w);

    short* dst = Wb + ((((size_t)j * NIP + ip) * NE + e) * 32) + isel * 16;
    *reinterpret_cast<bfrag*>(dst)     = lo;
    *reinterpret_cast<bfrag*>(dst + 8) = hi;
}

// convx_k: x fp32 -> xb bf16, same [NB][NI][ND] layout. 8 elems/thread.
__global__ __launch_bounds__(256) void convx_k(const float* __restrict__ x,
                                               short* __restrict__ xb)
{
    const size_t t = (size_t)blockIdx.x * 256 + threadIdx.x;  // 262144 threads
    const float4* src = reinterpret_cast<const float4*>(x + t * 8);
    float4 a = src[0], b = src[1];
    bfrag v;
    v[0] = f2bf(a.x); v[1] = f2bf(a.y); v[2] = f2bf(a.z); v[3] = f2bf(a.w);
    v[4] = f2bf(b.x); v[5] = f2bf(b.y); v[6] = f2bf(b.z); v[7] = f2bf(b.w);
    *reinterpret_cast<bfrag*>(xb + t * 8) = v;
}

// ---------------------------------------------------------------------------
// logits_k: lgt[j][i][b] = sum_e Oacc[b,j,e] * u_hat[b,j,i,e]
// u_hat via mfma_16x16x32_bf16, K zero-padded (d=16). All operands bf16.
// grid (j=32, i-chunk=64 of 32), block 256 = 4 waves; wave = 16-b M-tile.
// Output layout [j][i][b]: each (j,i) row is a contiguous 256B run written
// by the block's 16 m==0 lanes as float4s (single-writer, coalesced-ish).
// ---------------------------------------------------------------------------
__global__ __launch_bounds__(256) void logits_k(
    const short* __restrict__ xb,     // [NB][NI][ND] bf16
    const short* __restrict__ Wb,     // [NJ][NIP][NE][32] bf16
    const float* __restrict__ Oacc,   // [NB][NJ][NE]
    float* __restrict__ lgt)          // [NJ][NI][NB]
{
    const int j    = blockIdx.x;
    const int i0   = blockIdx.y * 32;
    const int t    = threadIdx.x;
    const int wv   = t >> 6;
    const int ln   = t & 63;
    const int m    = ln & 15;
    const int quad = ln >> 4;

    // Hoist Oacc fragments: rows b = wv*16 + quad*4 + r, cols e = m / 16+m
    float O0[4], O1[4];
#pragma unroll
    for (int r = 0; r < 4; ++r) {
        int b = wv * 16 + quad * 4 + r;
        O0[r] = Oacc[((size_t)b * NJ + j) * NE + m];
        O1[r] = Oacc[((size_t)b * NJ + j) * NE + 16 + m];
    }

    const int  bA  = wv * 16 + m;   // A-operand row (b) this lane supplies
    const bool act = quad < 2;      // quads 0,1 carry k=0..15 (d); 2,3 zero pad
    const int  d0  = quad * 8;

#pragma unroll 2
    for (int il = 0; il < 32; ++il) {
        const int i = i0 + il;
        const int ip = i >> 1, isel = i & 1;
        bfrag av = (bfrag)0, bv0 = (bfrag)0, bv1 = (bfrag)0;
        if (act) {
            av = *reinterpret_cast<const bfrag*>(
                xb + ((size_t)bA * NI + i) * ND + d0);
            const short* wp = Wb + (((size_t)j * NIP + ip) * NE + m) * 32
                                 + isel * 16 + d0;
            bv0 = *reinterpret_cast<const bfrag*>(wp);
            bv1 = *reinterpret_cast<const bfrag*>(wp + 16 * 32);
        }
        f32x4 z = {0.f, 0.f, 0.f, 0.f};
        f32x4 U0 = __builtin_amdgcn_mfma_f32_16x16x32_bf16(av, bv0, z, 0, 0, 0);
        f32x4 U1 = __builtin_amdgcn_mfma_f32_16x16x32_bf16(av, bv1, z, 0, 0, 0);

        float lp[4];
#pragma unroll
        for (int r = 0; r < 4; ++r) {
            float v = fmaf(U0[r], O0[r], U1[r] * O1[r]);
            v = rot16_add<1>(v);
            v = rot16_add<2>(v);
            v = rot16_add<4>(v);
            v = rot16_add<8>(v);
            lp[r] = v;   // full sum over 32 e's, replicated across the 16-lane row
        }
        if (m == 0) {
            // b = wv*16 + quad*4 + r, r=0..3 -> contiguous float4
            float4 o = make_float4(lp[0], lp[1], lp[2], lp[3]);
            *reinterpret_cast<float4*>(
                lgt + ((size_t)j * NI + i) * NB + wv * 16 + quad * 4) = o;
        }
    }
}

// ---------------------------------------------------------------------------
// softmax_k: softmax over j on [j][i][b] layout, in place. One thread per
// (i,b) pair; consecutive threads -> consecutive b (coalesced).
// grid (NB*NI/256).
// ---------------------------------------------------------------------------
__global__ __launch_bounds__(256) void softmax_k(float* __restrict__ lgt)
{
    const size_t tid = (size_t)blockIdx.x * 256 + threadIdx.x;  // (i,b)
    float* base = lgt + tid;      // lgt[j][tid], stride NI*NB between j's

    float v[NJ];
    float mx = -1e30f;
#pragma unroll
    for (int jj = 0; jj < NJ; ++jj) {
        v[jj] = base[(size_t)jj * NI * NB];
        mx = fmaxf(mx, v[jj]);
    }
    float sum = 0.f;
#pragma unroll
    for (int jj = 0; jj < NJ; ++jj) {
        v[jj] = __expf(v[jj] - mx);
        sum += v[jj];
    }
    const float inv = 1.0f / sum;
#pragma unroll
    for (int jj = 0; jj < NJ; ++jj) base[(size_t)jj * NI * NB] = v[jj] * inv;
}

// ---------------------------------------------------------------------------
// wsum_k: s[b,j,e] += sum_i c[j,i,b] * u_hat[b,j,i,e]
// A[b][k] = c*x (fp32 mul + packed bf16 cvt), B[e][k] = Wb (preconverted).
// K=32 chunk = 2 i's. Split-K over 64 chunks, atomicAdd tail.
// grid (j=32, kc=64), block 128 = 2 waves; wave = 2 M-tiles.
// ---------------------------------------------------------------------------
template <bool R0>
__global__ __launch_bounds__(128) void wsum_k(
    const float* __restrict__ x,      // [NB][NI][ND] fp32
    const short* __restrict__ Wb,     // [NJ][NIP][NE][32] bf16
    const float* __restrict__ c,      // [NJ][NI][NB], unused if R0
    float* __restrict__ s)            // [NB][NJ][NE]
{
    const int j    = blockIdx.x;
    const int ip0  = blockIdx.y * 16;  // 16 i-pairs = 32 i's
    const int t    = threadIdx.x;
    const int wv   = t >> 6;
    const int ln   = t & 63;
    const int m    = ln & 15;
    const int quad = ln >> 4;
    const int isel = quad >> 1;        // which of the 2 i's in the K-chunk
    const int d0   = (quad & 1) * 8;   // which 8 d's

    f32x4 acc[2][2];
#pragma unroll
    for (int a = 0; a < 2; ++a)
#pragma unroll
        for (int n = 0; n < 2; ++n) acc[a][n] = (f32x4){0.f, 0.f, 0.f, 0.f};

#pragma unroll 4
    for (int it = 0; it < 16; ++it) {
        const int ip = ip0 + it;
        const int ia = ip * 2 + isel;
        const short* wp = Wb + (((size_t)j * NIP + ip) * NE + m) * 32 + quad * 8;
        bfrag bv0 = *reinterpret_cast<const bfrag*>(wp);
        bfrag bv1 = *reinterpret_cast<const bfrag*>(wp + 16 * 32);
#pragma unroll
        for (int mt = 0; mt < 2; ++mt) {
            const int b = (wv * 2 + mt) * 16 + m;
            // coalesced: consecutive m-lanes -> consecutive b
            const float cc = R0 ? (1.0f / NJ)
                                : c[((size_t)j * NI + ia) * NB + b];
            const float4* xp = reinterpret_cast<const float4*>(
                x + ((size_t)b * NI + ia) * ND + d0);
            float4 x0 = xp[0], x1 = xp[1];
            bfrag av;
            unsigned* avu = reinterpret_cast<unsigned*>(&av);
            avu[0] = pk2bf(x0.x * cc, x0.y * cc);
            avu[1] = pk2bf(x0.z * cc, x0.w * cc);
            avu[2] = pk2bf(x1.x * cc, x1.y * cc);
            avu[3] = pk2bf(x1.z * cc, x1.w * cc);
            acc[mt][0] = __builtin_amdgcn_mfma_f32_16x16x32_bf16(av, bv0, acc[mt][0], 0, 0, 0);
            acc[mt][1] = __builtin_amdgcn_mfma_f32_16x16x32_bf16(av, bv1, acc[mt][1], 0, 0, 0);
        }
    }

#pragma unroll
    for (int mt = 0; mt < 2; ++mt)
#pragma unroll
        for (int nt = 0; nt < 2; ++nt)
#pragma unroll
            for (int r = 0; r < 4; ++r) {
                const int b = (wv * 2 + mt) * 16 + quad * 4 + r;
                const int e = nt * 16 + m;
                atomicAdd(&s[((size_t)b * NJ + j) * NE + e], acc[mt][nt][r]);
            }
}

// ---------------------------------------------------------------------------
// squash_k: squash(s) -> out or Oacc accumulation; re-zeros s for next round.
// ---------------------------------------------------------------------------
__global__ void squash_k(float* __restrict__ s, float* __restrict__ Oacc,
                         float* __restrict__ out, int final_round)
{
    const int b = blockIdx.x;
    const int t = threadIdx.x;
    const int j = t >> 3;
    const int eq = t & 7;
    const size_t off = ((size_t)b * NJ + j) * NE + 4 * eq;

    float4* sp = reinterpret_cast<float4*>(s + off);
    float4 v = *sp;
    *sp = make_float4(0.f, 0.f, 0.f, 0.f);

    float p = v.x * v.x + v.y * v.y + v.z * v.z + v.w * v.w;
    p += __shfl_xor(p, 1, 8);
    p += __shfl_xor(p, 2, 8);
    p += __shfl_xor(p, 4, 8);

    const float scale = p / ((1.0f + p) * sqrtf(p + 1e-7f));
    float4 o = make_float4(scale * v.x, scale * v.y, scale * v.z, scale * v.w);

    if (final_round) {
        *reinterpret_cast<float4*>(out + off) = o;
    } else {
        float4* op = reinterpret_cast<float4*>(Oacc + off);
        float4 ov = *op;
        *op = make_float4(ov.x + o.x, ov.y + o.y, ov.z + o.z, ov.w + o.w);
    }
}

extern "C" void kernel_launch(void* const* d_in, const int* in_sizes, int n_in,
                              void* d_out, int out_size, void* d_ws, size_t ws_size,
                              hipStream_t stream)
{
    (void)in_sizes; (void)n_in; (void)out_size; (void)ws_size;
    const float* x = (const float*)d_in[0];   // [64][2048][16]
    const float* W = (const float*)d_in[1];   // [32][2048][32][16]
    float* out = (float*)d_out;               // [64][32][32]

    // ws layout (≈84.5 MB):
    float* s    = (float*)d_ws;                       // 64K floats   (256 KB)
    float* Oacc = s + NB * NJ * NE;                   // 64K floats   (256 KB)
    float* lgt  = Oacc + NB * NJ * NE;                // [NJ][NI][NB] (16 MB)
    short* xb   = (short*)(lgt + (size_t)NB * NJ * NI);        // 2M bf16 (4 MB)
    short* Wb   = xb + (size_t)NB * NI * ND;                   // 32M bf16 (64 MB)

    // zero s and Oacc (ws is poisoned to 0xAA before every launch)
    hipMemsetAsync(d_ws, 0, (size_t)2 * NB * NJ * NE * sizeof(float), stream);

    // pre-convert W and x to bf16 (fragment layouts)
    convw_k<<<(NJ * NIP * NE * 2) / 256, 256, 0, stream>>>(W, Wb);
    convx_k<<<(NB * NI * ND / 8) / 256, 256, 0, stream>>>(x, xb);

    dim3 gG(NJ, NI / 32);   // 32 x 64 blocks

    // round 0: uniform c = 1/32
    wsum_k<true><<<gG, 128, 0, stream>>>(x, Wb, lgt, s);
    squash_k<<<NB, 256, 0, stream>>>(s, Oacc, out, 0);

    // round 1
    logits_k<<<gG, 256, 0, stream>>>(xb, Wb, Oacc, lgt);
    softmax_k<<<NB * NI / 256, 256, 0, stream>>>(lgt);
    wsum_k<false><<<gG, 128, 0, stream>>>(x, Wb, lgt, s);
    squash_k<<<NB, 256, 0, stream>>>(s, Oacc, out, 0);

    // round 2
    logits_k<<<gG, 256, 0, stream>>>(xb, Wb, Oacc, lgt);
    softmax_k<<<NB * NI / 256, 256, 0, stream>>>(lgt);
    wsum_k<false><<<gG, 128, 0, stream>>>(x, Wb, lgt, s);
    squash_k<<<NB, 256, 0, stream>>>(s, Oacc, out, 1);
}